// Round 12
// baseline (72.443 us; speedup 1.0000x reference)
//
#include <hip/hip_runtime.h>
#include <cfloat>
#include <cstdint>

#define NSEG 512
#define C 21
#define PPB 512                   // points per chunk
#define EPS_PICK 1e-3f            // >= 2*deltaM (MFMA emu) and >= deltaM+delta32 (filter)

typedef short short8 __attribute__((ext_vector_type(8)));     // 8 bf16 (MFMA A/B frag)
typedef float f32x4 __attribute__((ext_vector_type(4)));      // MFMA acc

// truncate r to bf16 (exact split: hi takes the top bits, r -= hi exact in f32)
__device__ inline unsigned short bsplit(float& r) {
    unsigned int u = __float_as_uint(r) & 0xFFFF0000u;
    r -= __uint_as_float(u);
    return (unsigned short)(u >> 16);
}

// ===================== K1: mfma + scatter =====================
// bid < MFMAB (2048): qb=bid&31, pc=bid>>5 — stage chunk pc (512 pts) as bf16 split
//   slots in LDS; 4 waves x 128 queries of emulated-f32 distance on the MATRIX pipe;
//   per-chunk min -> pbvT[q][pc].  (identical math to R6-R11, absmax 0.0 validated)
// bid >= MFMAB: scatter chunk sb — self-contained stable counting sort of d_points
//   (256 threads, pairwise scan); sb==0 also writes segbase[].
// K-slot layout (K=32, 21 used), per coord c (a=-2*p_c, b=q_c):
//   slots 6c..6c+5: A=[ah,ah,al,al,ah,a2]  B=[bh,bl,bh,bl,b2,bh]
//   slots 18..20:   A=|p|^2 hi/lo/lo2  B=[1,1,1];  slots 21..31: 0
__global__ __launch_bounds__(256, 4)
void k1_mfma_scatter(const float* __restrict__ pts, const float* __restrict__ dpts,
                     const int* __restrict__ sptids,
                     float4* __restrict__ pts4, float* __restrict__ pbvT,
                     int* __restrict__ segbase, int* __restrict__ sorted_orig,
                     float* __restrict__ out, int n, int m, int MFMAB)
{
    __shared__ short8 abuf[2048];                 // 32 KB (mfma A-tile / scatter scratch)
    const int t = threadIdx.x;

    if ((int)blockIdx.x >= MFMAB) {
        // ---- scatter chunk sb: stable counting sort, 256 threads ----
        int sb = blockIdx.x - MFMAB;
        int* Hb   = (int*)abuf;                   // [512] counts with idx < sb*256
        int* Ht   = Hb + NSEG;                    // [512] total counts
        int* pair = Ht + NSEG;                    // [256] pair sums for scan
        int* segs = pair + 256;                   // [256] this chunk's sptids
        Hb[t] = 0; Hb[t + 256] = 0; Ht[t] = 0; Ht[t + 256] = 0;
        __syncthreads();
        int before = sb * 256;
        for (int idx = t; idx < m; idx += 256) {  // integer LDS atomics -> deterministic
            int s = sptids[idx];
            atomicAdd(&Ht[s], 1);
            if (idx < before) atomicAdd(&Hb[s], 1);
        }
        __syncthreads();
        int e0 = Ht[2 * t], e1 = Ht[2 * t + 1];
        int v = e0 + e1;
        pair[t] = v;
        __syncthreads();
        for (int off = 1; off < 256; off <<= 1) { // inclusive scan of pair sums
            int add = (t >= off) ? pair[t - off] : 0;
            __syncthreads();
            v += add; pair[t] = v;
            __syncthreads();
        }
        int prev = (t > 0) ? pair[t - 1] : 0;
        int b0 = prev;                            // exclusive base of bin 2t
        int b1 = prev + e0;                       // exclusive base of bin 2t+1
        if (sb == 0) { segbase[2 * t] = b0; segbase[2 * t + 1] = b1; }
        int hb0 = Hb[2 * t], hb1 = Hb[2 * t + 1];
        __syncthreads();                          // all Hb reads done before overwrite
        Hb[2 * t] = b0 + hb0;                     // write base for THIS chunk
        Hb[2 * t + 1] = b1 + hb1;
        int i = sb * 256 + t;
        segs[t] = (i < m) ? sptids[i] : -1;
        __syncthreads();
        if (i < m) {
            int seg = segs[t];
            int rank = 0;
            for (int j = 0; j < t; j++) rank += (segs[j] == seg) ? 1 : 0;  // stable
            int pos = Hb[seg] + rank;
            out[pos * 3 + 0] = dpts[i * 3 + 0];
            out[pos * 3 + 1] = dpts[i * 3 + 1];
            out[pos * 3 + 2] = dpts[i * 3 + 2];
            sorted_orig[pos] = i;
        }
        return;
    }

    // ---- MFMA block ----
    const int wave = t >> 6, lane = t & 63;
    const int qb = blockIdx.x & 31, pc = blockIdx.x >> 5;

    short8 bq[8];                                 // B-frags from raw dpts
    {
        const short ONE = (short)0x3F80;          // bf16 1.0
#pragma unroll
        for (int f = 0; f < 8; f++) {
            int qf = qb * 512 + wave * 128 + f * 16 + (lane & 15);
            float b0 = dpts[qf * 3 + 0], b1 = dpts[qf * 3 + 1], b2c = dpts[qf * 3 + 2];
            float r;
            r = b0;  unsigned short bh0 = bsplit(r), bl0 = bsplit(r), b20 = bsplit(r);
            r = b1;  unsigned short bh1 = bsplit(r), bl1 = bsplit(r), b21 = bsplit(r);
            r = b2c; unsigned short bh2 = bsplit(r), bl2 = bsplit(r), b22 = bsplit(r);
            short8 g0 = {(short)bh0,(short)bl0,(short)bh0,(short)bl0,(short)b20,(short)bh0,(short)bh1,(short)bl1};
            short8 g1 = {(short)bh1,(short)bl1,(short)b21,(short)bh1,(short)bh2,(short)bl2,(short)bh2,(short)bl2};
            short8 g2 = {(short)b22,(short)bh2,ONE,ONE,ONE,0,0,0};
            short8 gz = {0,0,0,0,0,0,0,0};
            int g = lane >> 4;
            bq[f] = (g == 0) ? g0 : (g == 1) ? g1 : (g == 2) ? g2 : gz;
        }
    }

#pragma unroll
    for (int half = 0; half < 2; half++) {        // stage points t and t+256 of chunk pc
        int j = half * 256 + t;
        int i = pc * PPB + j;
        float x = pts[i * 3 + 0], y = pts[i * 3 + 1], z = pts[i * 3 + 2];
        float r;
        float a0 = -2.f * x, a1 = -2.f * y, a2f = -2.f * z;   // exact in f32
        r = a0;  unsigned short ah0 = bsplit(r), al0 = bsplit(r), a20 = bsplit(r);
        r = a1;  unsigned short ah1 = bsplit(r), al1 = bsplit(r), a21 = bsplit(r);
        r = a2f; unsigned short ah2 = bsplit(r), al2 = bsplit(r), a22 = bsplit(r);
        double pr = (double)x * x + (double)y * y + (double)z * z;
        float f0 = (float)pr;
        unsigned int u0 = __float_as_uint(f0) & 0xFFFF0000u;
        pr -= (double)__uint_as_float(u0);
        float f1 = (float)pr;
        unsigned int u1 = __float_as_uint(f1) & 0xFFFF0000u;
        pr -= (double)__uint_as_float(u1);
        float f2 = (float)pr;
        unsigned int u2 = __float_as_uint(f2) & 0xFFFF0000u;
        unsigned short s0 = (unsigned short)(u0 >> 16);
        unsigned short s1 = (unsigned short)(u1 >> 16);
        unsigned short s2 = (unsigned short)(u2 >> 16);
        short8 g0 = {(short)ah0,(short)ah0,(short)al0,(short)al0,(short)ah0,(short)a20,(short)ah1,(short)ah1};
        short8 g1 = {(short)al1,(short)al1,(short)ah1,(short)a21,(short)ah2,(short)ah2,(short)al2,(short)al2};
        short8 g2 = {(short)ah2,(short)a22,(short)s0,(short)s1,(short)s2,0,0,0};
        short8 gz = {0,0,0,0,0,0,0,0};
        int base = (j >> 4) * 64 + (j & 15);
        abuf[base + 0]  = g0;
        abuf[base + 16] = g1;
        abuf[base + 32] = g2;
        abuf[base + 48] = gz;
        if (qb == 0)                              // pts4 written exactly once per point
            pts4[i] = make_float4(x, y, z, fmaf(x, x, fmaf(y, y, z * z)));
    }
    __syncthreads();

    float run[8];
#pragma unroll
    for (int f = 0; f < 8; f++) run[f] = FLT_MAX;
    const f32x4 zero = {0.f, 0.f, 0.f, 0.f};
#pragma unroll 2
    for (int tt = 0; tt < 32; tt++) {
        short8 a = abuf[tt * 64 + lane];          // lane-contiguous b128: conflict-free
        f32x4 acc[8];
#pragma unroll
        for (int f = 0; f < 8; f++)               // 8 independent MFMAs in flight
            acc[f] = __builtin_amdgcn_mfma_f32_16x16x32_bf16(a, bq[f], zero, 0, 0, 0);
#pragma unroll
        for (int f = 0; f < 8; f++) {             // then fold (v_min3 x2)
            float t1 = fminf(fminf(acc[f][0], acc[f][1]), acc[f][2]);
            run[f] = fminf(fminf(t1, acc[f][3]), run[f]);
        }
    }
#pragma unroll
    for (int f = 0; f < 8; f++) {                 // merge 4 row-groups, write chunk min
        float v = run[f];
        v = fminf(v, __shfl_xor(v, 16, 64));
        v = fminf(v, __shfl_xor(v, 32, 64));
        if (lane < 16)
            pbvT[(size_t)(qb * 512 + wave * 128 + f * 16 + lane) * 64 + pc] = v;
    }
}

// ===================== K2: seg_pick_final =====================
// One block per segment (8 waves). Each wave resolves the NN for its members
// (j = base+wave, step 8): lane pc reads pbvT[q][pc], butterfly min -> g1,
// ballot(v<=g1+EPS) -> chunk mask, f32-filtered exact f64 resolve with
// lowest-index tie-break (== full f64 argmin, validated R1-R11). Lane c<21
// accumulates scores[nn][c] in f64 in fixed (j, wave) order -> deterministic.
// Block reduce (fixed wave order) -> argmax (strict >, first max wins) ->
// labels written to original positions. argmax(sum) == argmax(mean).
__global__ __launch_bounds__(512)
void k2_seg_pick(const float4* __restrict__ pts4, const float* __restrict__ dpts,
                 const float* __restrict__ scores, const float* __restrict__ pbvT,
                 const int* __restrict__ segbase, const int* __restrict__ sorted_orig,
                 float* __restrict__ out, int n, int m)
{
    __shared__ double wsum[8][C];
    __shared__ double total[C];
    __shared__ float lab;
    const int t = threadIdx.x, wave = t >> 6, lane = t & 63;
    const int s = blockIdx.x;
    const int base = segbase[s];
    const int end  = (s == NSEG - 1) ? m : segbase[s + 1];

    double acc = 0.0;                             // channel `lane` partial (lanes 0..20)
    for (int j = base + wave; j < end; j += 8) {
        int q = sorted_orig[j];
        float myv = pbvT[(size_t)q * 64 + lane];  // chunk `lane` min (coalesced 256B)
        float g1 = myv;
#pragma unroll
        for (int off = 1; off < 64; off <<= 1) g1 = fminf(g1, __shfl_xor(g1, off, 64));
        float thr = g1 + EPS_PICK;
        unsigned long long msk = __ballot(myv <= thr);   // bit pc == chunk qualifies

        float fx = dpts[q * 3 + 0], fy = dpts[q * 3 + 1], fz = dpts[q * 3 + 2];
        float fm2x = -2.f * fx, fm2y = -2.f * fy, fm2z = -2.f * fz;
        double m2x = -2.0 * (double)fx, m2y = -2.0 * (double)fy, m2z = -2.0 * (double)fz;
        double best = 1e308; int bi = 0x7fffffff;
        while (msk) {
            int pc = __builtin_ctzll(msk); msk &= msk - 1;
            int pbase = pc * PPB + lane;
#pragma unroll
            for (int r2 = 0; r2 < PPB / 64; r2++) {
                int i = pbase + r2 * 64;
                if (i < n) {
                    float4 p = pts4[i];
                    float v = fmaf(p.x, fm2x, fmaf(p.y, fm2y, fmaf(p.z, fm2z, p.w)));
                    if (v <= thr) {
                        double ps = (double)p.x * p.x + (double)p.y * p.y + (double)p.z * p.z;
                        double dv = fma((double)p.x, m2x, fma((double)p.y, m2y,
                                    fma((double)p.z, m2z, ps)));
                        if (dv < best || (dv == best && i < bi)) { best = dv; bi = i; }
                    }
                }
            }
        }
#pragma unroll
        for (int off = 32; off; off >>= 1) {
            double ov = __shfl_down(best, off, 64);
            int oi = __shfl_down(bi, off, 64);
            if (ov < best || (ov == best && oi < bi)) { best = ov; bi = oi; }
        }
        int bi0 = __shfl(bi, 0, 64);              // broadcast winner index
        if (lane < C)
            acc += (double)scores[(size_t)bi0 * C + lane];
    }
    if (lane < C) wsum[wave][lane] = acc;         // all 8 waves write (0.0 if no members)
    __syncthreads();
    if (t < C) {
        double tv = 0.0;
#pragma unroll
        for (int w = 0; w < 8; w++) tv += wsum[w][t];   // fixed wave order
        total[t] = tv;
    }
    __syncthreads();
    if (t == 0) {
        double bv = total[0]; int best = 0;
        for (int c = 1; c < C; c++)
            if (total[c] > bv) { bv = total[c]; best = c; }  // strict >: first max wins
        lab = (float)best;
    }
    __syncthreads();
    float fb = lab;
    for (int j = base + t; j < end; j += 512)     // labels in ORIGINAL order
        out[(size_t)m * 3 + sorted_orig[j]] = fb;
}

extern "C" void kernel_launch(void* const* d_in, const int* in_sizes, int n_in,
                              void* d_out, int out_size, void* d_ws, size_t ws_size,
                              hipStream_t stream) {
    const float* points = (const float*)d_in[0];
    const float* scores = (const float*)d_in[1];
    const float* dpts   = (const float*)d_in[2];
    const int*   sptids = (const int*)d_in[3];

    int n = in_sizes[0] / 3;          // 32768
    int m = in_sizes[2] / 3;          // 16384
    int QB    = (m + 511) / 512;      // 32 query blocks
    int PCg   = (n + 511) / 512;      // 64 point chunks
    int MFMAB = QB * PCg;             // 2048 mfma blocks
    int NCH   = (m + 255) / 256;      // 64 scatter chunks

    char* ws = (char*)d_ws;
    float4* pts4        = (float4*)ws;  ws += (size_t)n * sizeof(float4);
    float*  pbvT        = (float*)ws;   ws += (size_t)m * 64 * sizeof(float);
    int*    segbase     = (int*)ws;     ws += (size_t)NSEG * sizeof(int);
    int*    sorted_orig = (int*)ws;     ws += (size_t)m * sizeof(int);

    k1_mfma_scatter<<<MFMAB + NCH, 256, 0, stream>>>(points, dpts, sptids,
                                                     pts4, pbvT, segbase, sorted_orig,
                                                     (float*)d_out, n, m, MFMAB);
    k2_seg_pick<<<NSEG, 512, 0, stream>>>(pts4, dpts, scores, pbvT,
                                          segbase, sorted_orig, (float*)d_out, n, m);
}